// Round 1
// baseline (1496.815 us; speedup 1.0000x reference)
//
#include <hip/hip_runtime.h>
#include <cstdint>
#include <cstddef>

// ---- problem constants ----
#define SEQ_L   4096
#define EMBED   1024
#define HEADS   16
#define WINSZ   128
#define SHIFTSZ 64
#define HD      64
#define NWIN    32
#define MTOT    32768          // B * L
#define ATT_SCALE 0.125f       // HD^-0.5

typedef __bf16 bf16x8 __attribute__((ext_vector_type(8)));
typedef float  f32x4  __attribute__((ext_vector_type(4)));

typedef __attribute__((address_space(3))) void       lds_void;
typedef const __attribute__((address_space(1))) void gbl_void;

// async global->LDS, 16B per lane; LDS dest is wave-uniform-base + lane*16
#define GLDS16(g, s) __builtin_amdgcn_global_load_lds((gbl_void*)(g), (lds_void*)(s), 16, 0, 0)

__device__ __forceinline__ unsigned short f2bf(float f) {
    unsigned int u = __float_as_uint(f);
    u += 0x7fffu + ((u >> 16) & 1u);   // round-to-nearest-even
    return (unsigned short)(u >> 16);
}

// ---------------- weight f32 -> bf16 ----------------
__launch_bounds__(256)
__global__ void wconv(const float* __restrict__ in, unsigned short* __restrict__ out, int n)
{
    const int i = (blockIdx.x * 256 + threadIdx.x) * 4;
    if (i < n) {
        const float4 v = *(const float4*)(in + i);
        ushort4 o;
        o.x = f2bf(v.x); o.y = f2bf(v.y); o.z = f2bf(v.z); o.w = f2bf(v.w);
        *(ushort4*)(out + i) = o;
    }
}

// ---------------- LayerNorm (optionally fused with roll) ----------------
// output row (b, lw) = LN(x[b, (lw + shift) mod L]) -> bf16
__launch_bounds__(256)
__global__ void ln_kernel(const float* __restrict__ x, const float* __restrict__ gw,
                          const float* __restrict__ gb, unsigned short* __restrict__ out,
                          int shift)
{
    const int row = blockIdx.x;                 // output row in [0, 32768)
    const int b   = row >> 12;                  // /4096
    const int lw  = row & 4095;
    const int src = (b << 12) | ((lw + shift) & 4095);
    const int t   = threadIdx.x;

    const float4 v = ((const float4*)(x + (size_t)src * EMBED))[t];
    float s = v.x + v.y + v.z + v.w;
    float q = v.x * v.x + v.y * v.y + v.z * v.z + v.w * v.w;
#pragma unroll
    for (int off = 32; off > 0; off >>= 1) {
        s += __shfl_down(s, off);
        q += __shfl_down(q, off);
    }
    __shared__ float ss[4], qq[4];
    if ((t & 63) == 0) { ss[t >> 6] = s; qq[t >> 6] = q; }
    __syncthreads();
    s = ss[0] + ss[1] + ss[2] + ss[3];
    q = qq[0] + qq[1] + qq[2] + qq[3];
    const float mean = s * (1.0f / 1024.0f);
    const float rstd = rsqrtf(q * (1.0f / 1024.0f) - mean * mean + 1e-5f);

    const float4 w4 = ((const float4*)gw)[t];
    const float4 b4 = ((const float4*)gb)[t];
    ushort4 o;
    o.x = f2bf((v.x - mean) * rstd * w4.x + b4.x);
    o.y = f2bf((v.y - mean) * rstd * w4.y + b4.y);
    o.z = f2bf((v.z - mean) * rstd * w4.z + b4.z);
    o.w = f2bf((v.w - mean) * rstd * w4.w + b4.w);
    ((ushort4*)(out + (size_t)row * EMBED))[t] = o;
}

// ---------------- GEMM: out[M,N] = A[M,K](bf16) * W[N,K]^T(bf16) + bias, epilogues ----------------
// EPI 0: bf16 out            (QKV)
// EPI 1: f32 out = x[rolled] + v, written at rolled row  (proj + residual + roll(+SHIFT))
// EPI 2: gelu(v) -> bf16     (MLP1)
// EPI 3: f32 out[idx] += v   (MLP2 residual, in-place on d_out)
template<int EPI>
__launch_bounds__(256, 2)
__global__ void gemm_bt(const unsigned short* __restrict__ A, const unsigned short* __restrict__ W,
                        const float* __restrict__ bias, void* __restrict__ outv,
                        const float* __restrict__ resid, int M, int N, int K)
{
    __shared__ __align__(16) unsigned short As[128 * 32];  // 8 KB
    __shared__ __align__(16) unsigned short Bs[128 * 32];  // 8 KB

    const int t  = threadIdx.x;
    const int l  = t & 63;
    const int w  = t >> 6;
    const int m0 = blockIdx.y * 128;
    const int n0 = blockIdx.x * 128;
    const int lr = l & 15;
    const int lk = (l >> 4) * 8;
    const int wr = (w >> 1) * 64;
    const int wc = (w & 1) * 64;

    f32x4 acc[4][4];
#pragma unroll
    for (int a = 0; a < 4; ++a)
#pragma unroll
        for (int b = 0; b < 4; ++b)
            acc[a][b] = (f32x4){0.f, 0.f, 0.f, 0.f};

    for (int k0 = 0; k0 < K; k0 += 32) {
#pragma unroll
        for (int i = 0; i < 2; ++i) {
            const int bo  = (t + i * 256) * 16;     // byte offset in 8KB tile
            const int row = bo >> 6;                // 64 B per row (32 bf16)
            const int ke  = (bo & 63) >> 1;         // element offset in row
            GLDS16(A + (size_t)(m0 + row) * K + k0 + ke, (char*)As + bo);
            GLDS16(W + (size_t)(n0 + row) * K + k0 + ke, (char*)Bs + bo);
        }
        __syncthreads();

        bf16x8 af[4], bw[4];
#pragma unroll
        for (int mi = 0; mi < 4; ++mi)
            af[mi] = *(const bf16x8*)(As + (wr + mi * 16 + lr) * 32 + lk);
#pragma unroll
        for (int ni = 0; ni < 4; ++ni)
            bw[ni] = *(const bf16x8*)(Bs + (wc + ni * 16 + lr) * 32 + lk);
#pragma unroll
        for (int mi = 0; mi < 4; ++mi)
#pragma unroll
            for (int ni = 0; ni < 4; ++ni)
                acc[mi][ni] = __builtin_amdgcn_mfma_f32_16x16x32_bf16(af[mi], bw[ni], acc[mi][ni], 0, 0, 0);
        __syncthreads();
    }

#pragma unroll
    for (int mi = 0; mi < 4; ++mi)
#pragma unroll
        for (int ni = 0; ni < 4; ++ni)
#pragma unroll
            for (int r = 0; r < 4; ++r) {
                const int m = m0 + wr + mi * 16 + (l >> 4) * 4 + r;
                const int n = n0 + wc + ni * 16 + lr;
                float v = acc[mi][ni][r] + bias[n];
                if constexpr (EPI == 0) {
                    ((unsigned short*)outv)[(size_t)m * N + n] = f2bf(v);
                } else if constexpr (EPI == 1) {
                    const int b  = m >> 12;
                    const int lw = m & 4095;
                    const int ll = (lw + SHIFTSZ) & 4095;
                    const size_t di = ((size_t)(b << 12) + ll) * (size_t)N + n;
                    ((float*)outv)[di] = resid[di] + v;
                } else if constexpr (EPI == 2) {
                    const float g = 0.5f * v * (1.0f + erff(v * 0.70710678118654752f));
                    ((unsigned short*)outv)[(size_t)m * N + n] = f2bf(g);
                } else {
                    float* o = (float*)outv;
                    const size_t di = (size_t)m * N + n;
                    o[di] = o[di] + v;
                }
            }
}

// ---------------- windowed attention: one block per (window, head) ----------------
__launch_bounds__(256, 2)
__global__ void attn_kernel(const unsigned short* __restrict__ qkv, const float* __restrict__ rpb,
                            unsigned short* __restrict__ outp)
{
    __shared__ __align__(16) unsigned short P[WINSZ][136];  // normalized probs, padded (+8)
    __shared__ __align__(16) unsigned short VT[HD][136];    // V^T, padded

    const int t   = threadIdx.x;
    const int l   = t & 63;
    const int w   = t >> 6;
    const int lr  = l & 15;
    const int lq  = l >> 4;
    const int lk  = lq * 8;
    const int blk = blockIdx.x;
    const int win = blk >> 4;        // 0..255  (b*NW + window)
    const int h   = blk & 15;
    const bool masked = ((win & (NWIN - 1)) == NWIN - 1);

    const unsigned short* qb = qkv + (size_t)(win * WINSZ) * (3 * EMBED) + h * HD;
    const unsigned short* kb = qb + EMBED;
    const unsigned short* vb = qb + 2 * EMBED;

    // stage V^T : VT[d][k] = V[k][d]
    for (int idx = t; idx < WINSZ * HD; idx += 256) {
        const int k = idx >> 6;
        const int d = idx & 63;
        VT[d][k] = vb[(size_t)k * (3 * EMBED) + d];
    }

    // QK^T : wave w owns rows [32w, 32w+32), all 128 cols
    const int mrow = w * 32;
    f32x4 sacc[2][8];
#pragma unroll
    for (int a = 0; a < 2; ++a)
#pragma unroll
        for (int b = 0; b < 8; ++b)
            sacc[a][b] = (f32x4){0.f, 0.f, 0.f, 0.f};

#pragma unroll
    for (int ks = 0; ks < 2; ++ks) {
        const int k0 = ks * 32;
        bf16x8 aq[2], bk8[8];
#pragma unroll
        for (int mi = 0; mi < 2; ++mi)
            aq[mi] = *(const bf16x8*)(qb + (size_t)(mrow + mi * 16 + lr) * (3 * EMBED) + k0 + lk);
#pragma unroll
        for (int ni = 0; ni < 8; ++ni)
            bk8[ni] = *(const bf16x8*)(kb + (size_t)(ni * 16 + lr) * (3 * EMBED) + k0 + lk);
#pragma unroll
        for (int mi = 0; mi < 2; ++mi)
#pragma unroll
            for (int ni = 0; ni < 8; ++ni)
                sacc[mi][ni] = __builtin_amdgcn_mfma_f32_16x16x32_bf16(aq[mi], bk8[ni], sacc[mi][ni], 0, 0, 0);
    }

    // in-register softmax per row (each 16-lane group owns one row per (mi,r))
#pragma unroll
    for (int mi = 0; mi < 2; ++mi)
#pragma unroll
        for (int r = 0; r < 4; ++r) {
            const int i = mrow + mi * 16 + lq * 4 + r;
            float v[8];
            float mx = -1e30f;
#pragma unroll
            for (int ni = 0; ni < 8; ++ni) {
                const int j = ni * 16 + lr;
                float sv = sacc[mi][ni][r] * ATT_SCALE + rpb[(j - i + WINSZ - 1) * HEADS + h];
                if (masked && ((i >= SHIFTSZ) != (j >= SHIFTSZ))) sv -= 100.0f;
                v[ni] = sv;
                mx = fmaxf(mx, sv);
            }
#pragma unroll
            for (int s = 1; s < 16; s <<= 1) mx = fmaxf(mx, __shfl_xor(mx, s));
            float sm = 0.f;
#pragma unroll
            for (int ni = 0; ni < 8; ++ni) {
                const float p = __expf(v[ni] - mx);
                v[ni] = p;
                sm += p;
            }
#pragma unroll
            for (int s = 1; s < 16; s <<= 1) sm += __shfl_xor(sm, s);
            const float rs = 1.0f / sm;
#pragma unroll
            for (int ni = 0; ni < 8; ++ni)
                P[i][ni * 16 + lr] = f2bf(v[ni] * rs);
        }

    __syncthreads();   // VT (cross-wave) + P visible

    // PV : wave w rows [32w, 32w+32), cols 0..63, K = 128
    f32x4 oacc[2][4];
#pragma unroll
    for (int a = 0; a < 2; ++a)
#pragma unroll
        for (int b = 0; b < 4; ++b)
            oacc[a][b] = (f32x4){0.f, 0.f, 0.f, 0.f};

#pragma unroll
    for (int ks = 0; ks < 4; ++ks) {
        const int k0 = ks * 32;
        bf16x8 ap[2], av[4];
#pragma unroll
        for (int mi = 0; mi < 2; ++mi)
            ap[mi] = *(const bf16x8*)(&P[mrow + mi * 16 + lr][k0 + lk]);
#pragma unroll
        for (int ni = 0; ni < 4; ++ni)
            av[ni] = *(const bf16x8*)(&VT[ni * 16 + lr][k0 + lk]);
#pragma unroll
        for (int mi = 0; mi < 2; ++mi)
#pragma unroll
            for (int ni = 0; ni < 4; ++ni)
                oacc[mi][ni] = __builtin_amdgcn_mfma_f32_16x16x32_bf16(ap[mi], av[ni], oacc[mi][ni], 0, 0, 0);
    }

    unsigned short* ob = outp + (size_t)(win * WINSZ) * EMBED + h * HD;
#pragma unroll
    for (int mi = 0; mi < 2; ++mi)
#pragma unroll
        for (int ni = 0; ni < 4; ++ni)
#pragma unroll
            for (int r = 0; r < 4; ++r) {
                const int i = mrow + mi * 16 + lq * 4 + r;
                const int d = ni * 16 + lr;
                ob[(size_t)i * EMBED + d] = f2bf(oacc[mi][ni][r]);
            }
}

// ---------------- launcher ----------------
extern "C" void kernel_launch(void* const* d_in, const int* in_sizes, int n_in,
                              void* d_out, int out_size, void* d_ws, size_t ws_size,
                              hipStream_t stream)
{
    const float* x      = (const float*)d_in[0];
    const float* qkv_w  = (const float*)d_in[1];
    const float* qkv_b  = (const float*)d_in[2];
    const float* proj_w = (const float*)d_in[3];
    const float* proj_b = (const float*)d_in[4];
    const float* rpb    = (const float*)d_in[5];
    const float* n1w    = (const float*)d_in[6];
    const float* n1b    = (const float*)d_in[7];
    const float* n2w    = (const float*)d_in[8];
    const float* n2b    = (const float*)d_in[9];
    const float* w1     = (const float*)d_in[10];
    const float* b1     = (const float*)d_in[11];
    const float* w2     = (const float*)d_in[12];
    const float* b2     = (const float*)d_in[13];
    float* out = (float*)d_out;

    // workspace layout (~280 MiB total)
    unsigned short* wqkv  = (unsigned short*)d_ws;                    // 3072*1024
    unsigned short* wproj = wqkv  + (size_t)3072 * 1024;              // 1024*1024
    unsigned short* wm1   = wproj + (size_t)1024 * 1024;              // 4096*1024
    unsigned short* wm2   = wm1   + (size_t)4096 * 1024;              // 4096*1024
    unsigned short* bufA  = wm2   + (size_t)4096 * 1024;              // 32768*1024 bf16: h / attnout / h2
    unsigned short* bufB  = bufA  + (size_t)MTOT * EMBED;             // 32768*3072 bf16: qkv / mlp hidden

    wconv<<<3072, 256, 0, stream>>>(qkv_w, wqkv, 3 * EMBED * EMBED);
    wconv<<<1024, 256, 0, stream>>>(proj_w, wproj, EMBED * EMBED);
    wconv<<<4096, 256, 0, stream>>>(w1, wm1, 4 * EMBED * EMBED);
    wconv<<<4096, 256, 0, stream>>>(w2, wm2, 4 * EMBED * EMBED);

    // h = LN1(x) rolled by -SHIFT
    ln_kernel<<<MTOT, 256, 0, stream>>>(x, n1w, n1b, bufA, SHIFTSZ);

    // qkv = h @ qkv_w^T + qkv_b
    gemm_bt<0><<<dim3(24, 256), 256, 0, stream>>>(bufA, wqkv, qkv_b, bufB, nullptr, MTOT, 3 * EMBED, EMBED);

    // windowed attention -> bufA (bf16, (BW*W, E))
    attn_kernel<<<4096, 256, 0, stream>>>(bufB, rpb, bufA);

    // x2 = x + roll(attn @ proj_w^T + proj_b, +SHIFT)   -> d_out (f32)
    gemm_bt<1><<<dim3(8, 256), 256, 0, stream>>>(bufA, wproj, proj_b, out, x, MTOT, EMBED, EMBED);

    // h2 = LN2(x2)
    ln_kernel<<<MTOT, 256, 0, stream>>>(out, n2w, n2b, bufA, 0);

    // MLP, chunked over rows to bound hidden buffer (2 x 16384 rows)
    for (int c = 0; c < 2; ++c) {
        const size_t r0 = (size_t)c * 16384;
        gemm_bt<2><<<dim3(32, 128), 256, 0, stream>>>(bufA + r0 * EMBED, wm1, b1, bufB, nullptr,
                                                      16384, 4 * EMBED, EMBED);
        gemm_bt<3><<<dim3(8, 128), 256, 0, stream>>>(bufB, wm2, b2, out + r0 * EMBED, nullptr,
                                                     16384, EMBED, 4 * EMBED);
    }
}

// Round 2
// 1276.290 us; speedup vs baseline: 1.1728x; 1.1728x over previous
//
#include <hip/hip_runtime.h>
#include <cstdint>
#include <cstddef>

// ---- problem constants ----
#define SEQ_L   4096
#define EMBED   1024
#define HEADS   16
#define WINSZ   128
#define SHIFTSZ 64
#define HD      64
#define NWIN    32
#define MTOT    32768          // B * L
#define ATT_SCALE 0.125f       // HD^-0.5

typedef __bf16 bf16x8 __attribute__((ext_vector_type(8)));
typedef float  f32x4  __attribute__((ext_vector_type(4)));

typedef __attribute__((address_space(3))) void       lds_void;
typedef const __attribute__((address_space(1))) void gbl_void;

// async global->LDS, 16B per lane; LDS dest is wave-uniform base + lane*16
#define GLDS16(g, s) __builtin_amdgcn_global_load_lds((gbl_void*)(g), (lds_void*)(s), 16, 0, 0)

__device__ __forceinline__ unsigned short f2bf(float f) {
    unsigned int u = __float_as_uint(f);
    u += 0x7fffu + ((u >> 16) & 1u);   // round-to-nearest-even
    return (unsigned short)(u >> 16);
}

// ---------------- weight f32 -> bf16 ----------------
__launch_bounds__(256)
__global__ void wconv(const float* __restrict__ in, unsigned short* __restrict__ out, int n)
{
    const int i = (blockIdx.x * 256 + threadIdx.x) * 4;
    if (i < n) {
        const float4 v = *(const float4*)(in + i);
        ushort4 o;
        o.x = f2bf(v.x); o.y = f2bf(v.y); o.z = f2bf(v.z); o.w = f2bf(v.w);
        *(ushort4*)(out + i) = o;
    }
}

// ---------------- LayerNorm (optionally fused with roll) ----------------
__launch_bounds__(256)
__global__ void ln_kernel(const float* __restrict__ x, const float* __restrict__ gw,
                          const float* __restrict__ gb, unsigned short* __restrict__ out,
                          int shift)
{
    const int row = blockIdx.x;
    const int b   = row >> 12;
    const int lw  = row & 4095;
    const int src = (b << 12) | ((lw + shift) & 4095);
    const int t   = threadIdx.x;

    const float4 v = ((const float4*)(x + (size_t)src * EMBED))[t];
    float s = v.x + v.y + v.z + v.w;
    float q = v.x * v.x + v.y * v.y + v.z * v.z + v.w * v.w;
#pragma unroll
    for (int off = 32; off > 0; off >>= 1) {
        s += __shfl_down(s, off);
        q += __shfl_down(q, off);
    }
    __shared__ float ss[4], qq[4];
    if ((t & 63) == 0) { ss[t >> 6] = s; qq[t >> 6] = q; }
    __syncthreads();
    s = ss[0] + ss[1] + ss[2] + ss[3];
    q = qq[0] + qq[1] + qq[2] + qq[3];
    const float mean = s * (1.0f / 1024.0f);
    const float rstd = rsqrtf(q * (1.0f / 1024.0f) - mean * mean + 1e-5f);

    const float4 w4 = ((const float4*)gw)[t];
    const float4 b4 = ((const float4*)gb)[t];
    ushort4 o;
    o.x = f2bf((v.x - mean) * rstd * w4.x + b4.x);
    o.y = f2bf((v.y - mean) * rstd * w4.y + b4.y);
    o.z = f2bf((v.z - mean) * rstd * w4.z + b4.z);
    o.w = f2bf((v.w - mean) * rstd * w4.w + b4.w);
    ((ushort4*)(out + (size_t)row * EMBED))[t] = o;
}

// ================= 256x256 8-phase GEMM (HK-style, plain HIP) =================
// out[M,N] = A[M,K](bf16) * W[N,K]^T(bf16) + bias, with epilogues:
// EPI 0: bf16 out (QKV) | EPI 1: f32 out=x[rolled]+v at rolled row (proj)
// EPI 2: gelu->bf16 (MLP1) | EPI 3: f32 out += v (MLP2 residual)
//
// 8 waves (2M x 4N), per-wave C = 128x64. LDS = 2buf x {A,B} x 2half x (128x64 bf16)
// = 128 KiB. Swizzle: byte ^= (row&7)<<4, applied inverse on global src (linear
// global_load_lds dest) and forward on ds_read.
// Staging schedule (tile t, buf b=t&1): p0:(t+1).A0->buf[b^1], p1:(t+1).A1,
// p2:(t+2).B0->buf[b], p3:(t+2).B1. End-of-tile s_waitcnt vmcnt(4) guarantees
// (t+1) fully landed (only (t+2).B* in flight). Every slot's last reader is
// >=1 barrier before its re-stage -> race-free.

__device__ __forceinline__ void stage_half(const unsigned short* __restrict__ g, int ldk,
                                           char* ldsbase, int tid)
{
    const int r  = tid >> 3;                    // 0..63
    const int cg = ((tid & 7) ^ (r & 7)) << 3;  // inverse-swizzled col (elems)
    GLDS16(g + (size_t)r        * ldk + cg, ldsbase + tid * 16);
    GLDS16(g + (size_t)(r + 64) * ldk + cg, ldsbase + 8192 + tid * 16);
}

__device__ __forceinline__ bf16x8 lds_frag(const char* half, int row, int koff)
{
    const int off = koff ^ ((row & 7) << 4);    // st-swizzle on read
    return *(const bf16x8*)(half + row * 128 + off);
}

template<int EPI>
__launch_bounds__(512, 2)
__global__ void gemm256(const unsigned short* __restrict__ A, const unsigned short* __restrict__ W,
                        const float* __restrict__ bias, void* __restrict__ outv,
                        const float* __restrict__ resid, int M, int N, int K)
{
    __shared__ __align__(16) char lds[131072];
    const int tid = threadIdx.x;
    const int l   = tid & 63, w = tid >> 6;
    const int wm  = w >> 2, wn = w & 3;          // 2 x 4 waves
    const int lr  = l & 15, hi = l >> 4;
    const int k0off = hi << 4;                   // byte offset of k-slice within row

    // XCD-aware bijective swizzle (all grids here are %8 == 0)
    int id = blockIdx.x;
    const int nwg = gridDim.x;
    id = (id & 7) * (nwg >> 3) + (id >> 3);
    const int Ntl = N >> 8;
    const int m0  = (id / Ntl) << 8;
    const int n0  = (id % Ntl) << 8;
    const int NT  = K >> 6;                      // K-tiles of 64

#define HTB(b, ab, h) (lds + ((((b) << 1 | (ab)) << 1 | (h)) << 14))

    // prologue: t0 {A0,A1,B0,B1}, t1 {B0,B1}  (12 loads); wait t0 (vmcnt(4))
    stage_half(A + (size_t)m0         * K,      K, HTB(0,0,0), tid);
    stage_half(A + (size_t)(m0 + 128) * K,      K, HTB(0,0,1), tid);
    stage_half(W + (size_t)n0         * K,      K, HTB(0,1,0), tid);
    stage_half(W + (size_t)(n0 + 128) * K,      K, HTB(0,1,1), tid);
    stage_half(W + (size_t)n0         * K + 64, K, HTB(1,1,0), tid);
    stage_half(W + (size_t)(n0 + 128) * K + 64, K, HTB(1,1,1), tid);
    asm volatile("s_waitcnt vmcnt(4)" ::: "memory");
    __builtin_amdgcn_s_barrier();

    f32x4 acc[8][4];
#pragma unroll
    for (int f = 0; f < 8; ++f)
#pragma unroll
        for (int n = 0; n < 4; ++n)
            acc[f][n] = (f32x4){0.f, 0.f, 0.f, 0.f};

    bf16x8 bf[4][2], af[2][2];

#define LOAD_A(F0)                                                         \
    af[0][0] = lds_frag(Ah, (F0) * 16 + lr,      k0off);                   \
    af[0][1] = lds_frag(Ah, (F0) * 16 + lr,      64 + k0off);              \
    af[1][0] = lds_frag(Ah, (F0) * 16 + 16 + lr, k0off);                   \
    af[1][1] = lds_frag(Ah, (F0) * 16 + 16 + lr, 64 + k0off);

#define MFMA_BLOCK(F0)                                                     \
    __builtin_amdgcn_s_barrier();                                          \
    asm volatile("s_waitcnt lgkmcnt(0)" ::: "memory");                     \
    __builtin_amdgcn_s_setprio(1);                                         \
    _Pragma("unroll")                                                      \
    for (int n = 0; n < 4; ++n) {                                          \
        acc[F0][n]     = __builtin_amdgcn_mfma_f32_16x16x32_bf16(af[0][0], bf[n][0], acc[F0][n], 0, 0, 0);     \
        acc[F0][n]     = __builtin_amdgcn_mfma_f32_16x16x32_bf16(af[0][1], bf[n][1], acc[F0][n], 0, 0, 0);     \
        acc[F0 + 1][n] = __builtin_amdgcn_mfma_f32_16x16x32_bf16(af[1][0], bf[n][0], acc[F0 + 1][n], 0, 0, 0); \
        acc[F0 + 1][n] = __builtin_amdgcn_mfma_f32_16x16x32_bf16(af[1][1], bf[n][1], acc[F0 + 1][n], 0, 0, 0); \
    }                                                                      \
    __builtin_amdgcn_s_setprio(0);

    for (int t = 0; t < NT; ++t) {
        const int b = t & 1;
        const char* Ah = HTB(b, 0, wm);
        const char* Bh = HTB(b, 1, wn >> 1);
        const int   br0 = (wn & 1) << 6;
        const unsigned short* An = A + (size_t)m0 * K + (t + 1) * 64;
        const unsigned short* Wn = W + (size_t)n0 * K + (t + 2) * 64;

        // ---- phase 0: B(all) + A f0,f1 ; stage (t+1).A0 ----
#pragma unroll
        for (int n = 0; n < 4; ++n) {
            bf[n][0] = lds_frag(Bh, br0 + n * 16 + lr, k0off);
            bf[n][1] = lds_frag(Bh, br0 + n * 16 + lr, 64 + k0off);
        }
        LOAD_A(0)
        if (t + 1 < NT) stage_half(An, K, HTB(b ^ 1, 0, 0), tid);
        MFMA_BLOCK(0)
        __builtin_amdgcn_s_barrier();

        // ---- phase 1: A f2,f3 ; stage (t+1).A1 ----
        LOAD_A(2)
        if (t + 1 < NT) stage_half(An + (size_t)128 * K, K, HTB(b ^ 1, 0, 1), tid);
        MFMA_BLOCK(2)
        __builtin_amdgcn_s_barrier();

        // ---- phase 2: A f4,f5 ; stage (t+2).B0 ----
        LOAD_A(4)
        if (t + 2 < NT) stage_half(Wn, K, HTB(b, 1, 0), tid);
        MFMA_BLOCK(4)
        __builtin_amdgcn_s_barrier();

        // ---- phase 3: A f6,f7 ; stage (t+2).B1 ; counted vmcnt ----
        LOAD_A(6)
        if (t + 2 < NT) stage_half(Wn + (size_t)128 * K, K, HTB(b, 1, 1), tid);
        MFMA_BLOCK(6)
        if (t + 2 < NT) { asm volatile("s_waitcnt vmcnt(4)" ::: "memory"); }
        else            { asm volatile("s_waitcnt vmcnt(0)" ::: "memory"); }
        __builtin_amdgcn_s_barrier();
    }
#undef LOAD_A
#undef MFMA_BLOCK
#undef HTB

    // ---- epilogue ----
    const int cb = n0 + wn * 64;
    float bv[4];
#pragma unroll
    for (int n = 0; n < 4; ++n) bv[n] = bias[cb + n * 16 + lr];

#pragma unroll
    for (int f = 0; f < 8; ++f) {
        const int mbase = m0 + wm * 128 + f * 16 + hi * 4;
#pragma unroll
        for (int n = 0; n < 4; ++n) {
            const int col = cb + n * 16 + lr;
#pragma unroll
            for (int r = 0; r < 4; ++r) {
                const int m = mbase + r;
                float v = acc[f][n][r] + bv[n];
                if constexpr (EPI == 0) {
                    ((unsigned short*)outv)[(size_t)m * N + col] = f2bf(v);
                } else if constexpr (EPI == 1) {
                    const int bb = m >> 12;
                    const int lw = m & 4095;
                    const int ll = (lw + SHIFTSZ) & 4095;
                    const size_t di = ((size_t)(bb << 12) + ll) * (size_t)N + col;
                    ((float*)outv)[di] = resid[di] + v;
                } else if constexpr (EPI == 2) {
                    const float g = 0.5f * v * (1.0f + erff(v * 0.70710678118654752f));
                    ((unsigned short*)outv)[(size_t)m * N + col] = f2bf(g);
                } else {
                    float* o = (float*)outv;
                    const size_t di = (size_t)m * N + col;
                    o[di] = o[di] + v;
                }
            }
        }
    }
}

// ---------------- windowed attention: one block per (window, head) ----------------
__launch_bounds__(256, 2)
__global__ void attn_kernel(const unsigned short* __restrict__ qkv, const float* __restrict__ rpb,
                            unsigned short* __restrict__ outp)
{
    __shared__ __align__(16) unsigned short P[WINSZ][136];
    __shared__ __align__(16) unsigned short VT[HD][136];

    const int t   = threadIdx.x;
    const int l   = t & 63;
    const int w   = t >> 6;
    const int lr  = l & 15;
    const int lq  = l >> 4;
    const int lk  = lq * 8;
    const int blk = blockIdx.x;
    const int win = blk >> 4;
    const int h   = blk & 15;
    const bool masked = ((win & (NWIN - 1)) == NWIN - 1);

    const unsigned short* qb = qkv + (size_t)(win * WINSZ) * (3 * EMBED) + h * HD;
    const unsigned short* kb = qb + EMBED;
    const unsigned short* vb = qb + 2 * EMBED;

    for (int idx = t; idx < WINSZ * HD; idx += 256) {
        const int k = idx >> 6;
        const int d = idx & 63;
        VT[d][k] = vb[(size_t)k * (3 * EMBED) + d];
    }

    const int mrow = w * 32;
    f32x4 sacc[2][8];
#pragma unroll
    for (int a = 0; a < 2; ++a)
#pragma unroll
        for (int b = 0; b < 8; ++b)
            sacc[a][b] = (f32x4){0.f, 0.f, 0.f, 0.f};

#pragma unroll
    for (int ks = 0; ks < 2; ++ks) {
        const int k0 = ks * 32;
        bf16x8 aq[2], bk8[8];
#pragma unroll
        for (int mi = 0; mi < 2; ++mi)
            aq[mi] = *(const bf16x8*)(qb + (size_t)(mrow + mi * 16 + lr) * (3 * EMBED) + k0 + lk);
#pragma unroll
        for (int ni = 0; ni < 8; ++ni)
            bk8[ni] = *(const bf16x8*)(kb + (size_t)(ni * 16 + lr) * (3 * EMBED) + k0 + lk);
#pragma unroll
        for (int mi = 0; mi < 2; ++mi)
#pragma unroll
            for (int ni = 0; ni < 8; ++ni)
                sacc[mi][ni] = __builtin_amdgcn_mfma_f32_16x16x32_bf16(aq[mi], bk8[ni], sacc[mi][ni], 0, 0, 0);
    }

#pragma unroll
    for (int mi = 0; mi < 2; ++mi)
#pragma unroll
        for (int r = 0; r < 4; ++r) {
            const int i = mrow + mi * 16 + lq * 4 + r;
            float v[8];
            float mx = -1e30f;
#pragma unroll
            for (int ni = 0; ni < 8; ++ni) {
                const int j = ni * 16 + lr;
                float sv = sacc[mi][ni][r] * ATT_SCALE + rpb[(j - i + WINSZ - 1) * HEADS + h];
                if (masked && ((i >= SHIFTSZ) != (j >= SHIFTSZ))) sv -= 100.0f;
                v[ni] = sv;
                mx = fmaxf(mx, sv);
            }
#pragma unroll
            for (int s = 1; s < 16; s <<= 1) mx = fmaxf(mx, __shfl_xor(mx, s));
            float sm = 0.f;
#pragma unroll
            for (int ni = 0; ni < 8; ++ni) {
                const float p = __expf(v[ni] - mx);
                v[ni] = p;
                sm += p;
            }
#pragma unroll
            for (int s = 1; s < 16; s <<= 1) sm += __shfl_xor(sm, s);
            const float rs = 1.0f / sm;
#pragma unroll
            for (int ni = 0; ni < 8; ++ni)
                P[i][ni * 16 + lr] = f2bf(v[ni] * rs);
        }

    __syncthreads();

    f32x4 oacc[2][4];
#pragma unroll
    for (int a = 0; a < 2; ++a)
#pragma unroll
        for (int b = 0; b < 4; ++b)
            oacc[a][b] = (f32x4){0.f, 0.f, 0.f, 0.f};

#pragma unroll
    for (int ks = 0; ks < 4; ++ks) {
        const int k0 = ks * 32;
        bf16x8 ap[2], av[4];
#pragma unroll
        for (int mi = 0; mi < 2; ++mi)
            ap[mi] = *(const bf16x8*)(&P[mrow + mi * 16 + lr][k0 + lk]);
#pragma unroll
        for (int ni = 0; ni < 4; ++ni)
            av[ni] = *(const bf16x8*)(&VT[ni * 16 + lr][k0 + lk]);
#pragma unroll
        for (int mi = 0; mi < 2; ++mi)
#pragma unroll
            for (int ni = 0; ni < 4; ++ni)
                oacc[mi][ni] = __builtin_amdgcn_mfma_f32_16x16x32_bf16(ap[mi], av[ni], oacc[mi][ni], 0, 0, 0);
    }

    unsigned short* ob = outp + (size_t)(win * WINSZ) * EMBED + h * HD;
#pragma unroll
    for (int mi = 0; mi < 2; ++mi)
#pragma unroll
        for (int ni = 0; ni < 4; ++ni)
#pragma unroll
            for (int r = 0; r < 4; ++r) {
                const int i = mrow + mi * 16 + lq * 4 + r;
                const int d = ni * 16 + lr;
                ob[(size_t)i * EMBED + d] = f2bf(oacc[mi][ni][r]);
            }
}

// ---------------- launcher ----------------
extern "C" void kernel_launch(void* const* d_in, const int* in_sizes, int n_in,
                              void* d_out, int out_size, void* d_ws, size_t ws_size,
                              hipStream_t stream)
{
    const float* x      = (const float*)d_in[0];
    const float* qkv_w  = (const float*)d_in[1];
    const float* qkv_b  = (const float*)d_in[2];
    const float* proj_w = (const float*)d_in[3];
    const float* proj_b = (const float*)d_in[4];
    const float* rpb    = (const float*)d_in[5];
    const float* n1w    = (const float*)d_in[6];
    const float* n1b    = (const float*)d_in[7];
    const float* n2w    = (const float*)d_in[8];
    const float* n2b    = (const float*)d_in[9];
    const float* w1     = (const float*)d_in[10];
    const float* b1     = (const float*)d_in[11];
    const float* w2     = (const float*)d_in[12];
    const float* b2     = (const float*)d_in[13];
    float* out = (float*)d_out;

    unsigned short* wqkv  = (unsigned short*)d_ws;                    // 3072*1024
    unsigned short* wproj = wqkv  + (size_t)3072 * 1024;              // 1024*1024
    unsigned short* wm1   = wproj + (size_t)1024 * 1024;              // 4096*1024
    unsigned short* wm2   = wm1   + (size_t)4096 * 1024;              // 4096*1024
    unsigned short* bufA  = wm2   + (size_t)4096 * 1024;              // 32768*1024
    unsigned short* bufB  = bufA  + (size_t)MTOT * EMBED;             // 32768*3072

    wconv<<<3072, 256, 0, stream>>>(qkv_w, wqkv, 3 * EMBED * EMBED);
    wconv<<<1024, 256, 0, stream>>>(proj_w, wproj, EMBED * EMBED);
    wconv<<<4096, 256, 0, stream>>>(w1, wm1, 4 * EMBED * EMBED);
    wconv<<<4096, 256, 0, stream>>>(w2, wm2, 4 * EMBED * EMBED);

    // h = LN1(x) rolled by -SHIFT
    ln_kernel<<<MTOT, 256, 0, stream>>>(x, n1w, n1b, bufA, SHIFTSZ);

    // qkv = h @ qkv_w^T + qkv_b   (M=32768, N=3072, K=1024) -> 128*12 = 1536 wgs
    gemm256<0><<<dim3(1536), 512, 0, stream>>>(bufA, wqkv, qkv_b, bufB, nullptr, MTOT, 3 * EMBED, EMBED);

    // windowed attention -> bufA
    attn_kernel<<<4096, 256, 0, stream>>>(bufB, rpb, bufA);

    // x2 = x + roll(attn @ proj_w^T + proj_b, +SHIFT)  (128*4 = 512 wgs)
    gemm256<1><<<dim3(512), 512, 0, stream>>>(bufA, wproj, proj_b, out, x, MTOT, EMBED, EMBED);

    // h2 = LN2(x2)
    ln_kernel<<<MTOT, 256, 0, stream>>>(out, n2w, n2b, bufA, 0);

    // MLP chunked (2 x 16384 rows): MLP1 64*16=1024 wgs, MLP2 64*4=256 wgs
    for (int c = 0; c < 2; ++c) {
        const size_t r0 = (size_t)c * 16384;
        gemm256<2><<<dim3(1024), 512, 0, stream>>>(bufA + r0 * EMBED, wm1, b1, bufB, nullptr,
                                                   16384, 4 * EMBED, EMBED);
        gemm256<3><<<dim3(256), 512, 0, stream>>>(bufB, wm2, b2, out + r0 * EMBED, nullptr,
                                                  16384, EMBED, 4 * EMBED);
    }
}

// Round 3
// 1229.759 us; speedup vs baseline: 1.2172x; 1.0378x over previous
//
#include <hip/hip_runtime.h>
#include <cstdint>
#include <cstddef>

// ---- problem constants ----
#define SEQ_L   4096
#define EMBED   1024
#define HEADS   16
#define WINSZ   128
#define SHIFTSZ 64
#define HD      64
#define NWIN    32
#define MTOT    32768          // B * L
#define ATT_SCALE 0.125f       // HD^-0.5

typedef __bf16 bf16x8 __attribute__((ext_vector_type(8)));
typedef float  f32x4  __attribute__((ext_vector_type(4)));

typedef __attribute__((address_space(3))) void       lds_void;
typedef const __attribute__((address_space(1))) void gbl_void;

// async global->LDS, 16B per lane; LDS dest is wave-uniform base + lane*16
#define GLDS16(g, s) __builtin_amdgcn_global_load_lds((gbl_void*)(g), (lds_void*)(s), 16, 0, 0)

__device__ __forceinline__ unsigned short f2bf(float f) {
    unsigned int u = __float_as_uint(f);
    u += 0x7fffu + ((u >> 16) & 1u);   // round-to-nearest-even
    return (unsigned short)(u >> 16);
}

// ---------------- weight f32 -> bf16 ----------------
__launch_bounds__(256)
__global__ void wconv(const float* __restrict__ in, unsigned short* __restrict__ out, int n)
{
    const int i = (blockIdx.x * 256 + threadIdx.x) * 4;
    if (i < n) {
        const float4 v = *(const float4*)(in + i);
        ushort4 o;
        o.x = f2bf(v.x); o.y = f2bf(v.y); o.z = f2bf(v.z); o.w = f2bf(v.w);
        *(ushort4*)(out + i) = o;
    }
}

// ---------------- LayerNorm, wave-per-row (optionally fused with roll) ----------------
__launch_bounds__(256)
__global__ void ln_kernel(const float* __restrict__ x, const float* __restrict__ gw,
                          const float* __restrict__ gb, unsigned short* __restrict__ out,
                          int shift)
{
    const int row  = blockIdx.x * 4 + (threadIdx.x >> 6);
    const int lane = threadIdx.x & 63;
    const int b    = row >> 12;
    const int lw   = row & 4095;
    const int src  = (b << 12) | ((lw + shift) & 4095);
    const float* xr = x + (size_t)src * EMBED;

    float4 v[4];
    float s = 0.f, q = 0.f;
#pragma unroll
    for (int j = 0; j < 4; ++j) {
        v[j] = ((const float4*)xr)[lane + j * 64];
        s += v[j].x + v[j].y + v[j].z + v[j].w;
        q += v[j].x * v[j].x + v[j].y * v[j].y + v[j].z * v[j].z + v[j].w * v[j].w;
    }
#pragma unroll
    for (int off = 32; off > 0; off >>= 1) {
        s += __shfl_xor(s, off);
        q += __shfl_xor(q, off);
    }
    const float mean = s * (1.0f / 1024.0f);
    const float rstd = rsqrtf(q * (1.0f / 1024.0f) - mean * mean + 1e-5f);

    unsigned short* orow = out + (size_t)row * EMBED;
#pragma unroll
    for (int j = 0; j < 4; ++j) {
        const float4 w4 = ((const float4*)gw)[lane + j * 64];
        const float4 b4 = ((const float4*)gb)[lane + j * 64];
        ushort4 o;
        o.x = f2bf((v[j].x - mean) * rstd * w4.x + b4.x);
        o.y = f2bf((v[j].y - mean) * rstd * w4.y + b4.y);
        o.z = f2bf((v[j].z - mean) * rstd * w4.z + b4.z);
        o.w = f2bf((v[j].w - mean) * rstd * w4.w + b4.w);
        ((ushort4*)orow)[lane + j * 64] = o;
    }
}

// ================= 256x256 8-phase GEMM, one-phase-ahead reg prefetch =================
// out[M,N] = A[M,K](bf16) * W[N,K]^T(bf16) + bias.
// EPI 0: bf16 out (QKV) | EPI 1: f32 out=x[rolled]+v at rolled row (proj)
// EPI 2: gelu->bf16 (MLP1) | EPI 3: f32 out += v (MLP2 residual)
//
// 8 waves (2M x 4N), per-wave C = 128x64. LDS = 128 KiB double-buffered.
// Swizzle byte ^= (row&7)<<4 : inverse on global src, forward on ds_read.
// Pipeline: MFMA(phase p, A-bank p&1) runs while phase p+1's A-subtile loads
// into the other bank; counted lgkmcnt(4) waits only the previous phase's
// reads. B-frags for tile t+1 prefetched after phase-3's MFMA (same regs).
// Stage slots: p0:(t+1).A0, p1:(t+1).A1, p2:(t+2).B0, p3:(t+2).B1.
// One counted vmcnt(2) per tile at p3 (leaves only (t+2).B0 in flight);
// tail tiles degrade counts to 0 (a fixed count would race).

__device__ __forceinline__ void stage_half(const unsigned short* __restrict__ g, int ldk,
                                           char* ldsbase, int tid)
{
    const int r  = tid >> 3;                    // 0..63
    const int cg = ((tid & 7) ^ (r & 7)) << 3;  // inverse-swizzled col (elems)
    GLDS16(g + (size_t)r        * ldk + cg, ldsbase + tid * 16);
    GLDS16(g + (size_t)(r + 64) * ldk + cg, ldsbase + 8192 + tid * 16);
}

__device__ __forceinline__ bf16x8 lds_frag(const char* half, int row, int koff)
{
    const int off = koff ^ ((row & 7) << 4);    // st-swizzle on read
    return *(const bf16x8*)(half + row * 128 + off);
}

template<int EPI>
__launch_bounds__(512, 2)
__global__ void gemm256(const unsigned short* __restrict__ A, const unsigned short* __restrict__ W,
                        const float* __restrict__ bias, void* __restrict__ outv,
                        const float* __restrict__ resid, int M, int N, int K)
{
    __shared__ __align__(16) char lds[131072];
    const int tid = threadIdx.x;
    const int l   = tid & 63, w = tid >> 6;
    const int wm  = w >> 2, wn = w & 3;          // 2 x 4 waves
    const int lr  = l & 15, hi = l >> 4;
    const int k0off = hi << 4;                   // byte offset of k-slice within row
    const int br0   = (wn & 1) << 6;

    // XCD-aware bijective swizzle (all grids here are %8 == 0)
    int id = blockIdx.x;
    const int nwg = gridDim.x;
    id = (id & 7) * (nwg >> 3) + (id >> 3);
    const int Ntl = N >> 8;
    const int m0  = (id / Ntl) << 8;
    const int n0  = (id % Ntl) << 8;
    const int NT  = K >> 6;                      // K-tiles of 64

#define HTB(b, ab, h) (lds + ((((b) << 1 | (ab)) << 1 | (h)) << 14))

    // prologue: t0 {A0,A1,B0,B1}, t1 {B0,B1}; drain t0 (vmcnt(4))
    stage_half(A + (size_t)m0         * K,      K, HTB(0,0,0), tid);
    stage_half(A + (size_t)(m0 + 128) * K,      K, HTB(0,0,1), tid);
    stage_half(W + (size_t)n0         * K,      K, HTB(0,1,0), tid);
    stage_half(W + (size_t)(n0 + 128) * K,      K, HTB(0,1,1), tid);
    stage_half(W + (size_t)n0         * K + 64, K, HTB(1,1,0), tid);
    stage_half(W + (size_t)(n0 + 128) * K + 64, K, HTB(1,1,1), tid);
    asm volatile("s_waitcnt vmcnt(4)" ::: "memory");
    __builtin_amdgcn_s_barrier();

    f32x4 acc[8][4];
#pragma unroll
    for (int f = 0; f < 8; ++f)
#pragma unroll
        for (int n = 0; n < 4; ++n)
            acc[f][n] = (f32x4){0.f, 0.f, 0.f, 0.f};

    bf16x8 bf[4][2], af0[2][2], af1[2][2];

#define LOAD_A_BANK(bank, AHP, F0)                                          \
    af##bank[0][0] = lds_frag(AHP, (F0) * 16 + lr,      k0off);             \
    af##bank[0][1] = lds_frag(AHP, (F0) * 16 + lr,      64 + k0off);        \
    af##bank[1][0] = lds_frag(AHP, (F0) * 16 + 16 + lr, k0off);             \
    af##bank[1][1] = lds_frag(AHP, (F0) * 16 + 16 + lr, 64 + k0off);

#define MFMA_BANK(bank, F0)                                                 \
    __builtin_amdgcn_s_setprio(1);                                          \
    _Pragma("unroll")                                                       \
    for (int n = 0; n < 4; ++n) {                                           \
        acc[F0][n]     = __builtin_amdgcn_mfma_f32_16x16x32_bf16(af##bank[0][0], bf[n][0], acc[F0][n], 0, 0, 0);         \
        acc[F0][n]     = __builtin_amdgcn_mfma_f32_16x16x32_bf16(af##bank[0][1], bf[n][1], acc[F0][n], 0, 0, 0);         \
        acc[(F0) + 1][n] = __builtin_amdgcn_mfma_f32_16x16x32_bf16(af##bank[1][0], bf[n][0], acc[(F0) + 1][n], 0, 0, 0); \
        acc[(F0) + 1][n] = __builtin_amdgcn_mfma_f32_16x16x32_bf16(af##bank[1][1], bf[n][1], acc[(F0) + 1][n], 0, 0, 0); \
    }                                                                       \
    __builtin_amdgcn_s_setprio(0);

    // pre-issue t0.p0 operands: B(0) + A-bank0 f0,f1
    {
        const char* Bh0 = HTB(0, 1, wn >> 1);
#pragma unroll
        for (int n = 0; n < 4; ++n) {
            bf[n][0] = lds_frag(Bh0, br0 + n * 16 + lr, k0off);
            bf[n][1] = lds_frag(Bh0, br0 + n * 16 + lr, 64 + k0off);
        }
        const char* Ah0 = HTB(0, 0, wm);
        LOAD_A_BANK(0, Ah0, 0)
    }

#define TILE(BUF)                                                              \
    {                                                                          \
        const char* Ah = HTB(BUF, 0, wm);                                      \
        const unsigned short* An = A + (size_t)m0 * K + (size_t)(t + 1) * 64;  \
        const unsigned short* Wn = W + (size_t)n0 * K + (size_t)(t + 2) * 64;  \
        /* ---- phase 0 ---- */                                                \
        LOAD_A_BANK(1, Ah, 2)                                                  \
        if (t + 1 < NT) stage_half(An, K, HTB(BUF ^ 1, 0, 0), tid);            \
        asm volatile("s_waitcnt lgkmcnt(4)" ::: "memory");                     \
        MFMA_BANK(0, 0)                                                        \
        __builtin_amdgcn_s_barrier();                                          \
        /* ---- phase 1 ---- */                                                \
        LOAD_A_BANK(0, Ah, 4)                                                  \
        if (t + 1 < NT) stage_half(An + (size_t)128 * K, K, HTB(BUF ^ 1, 0, 1), tid); \
        asm volatile("s_waitcnt lgkmcnt(4)" ::: "memory");                     \
        MFMA_BANK(1, 2)                                                        \
        __builtin_amdgcn_s_barrier();                                          \
        /* ---- phase 2 ---- */                                                \
        LOAD_A_BANK(1, Ah, 6)                                                  \
        if (t + 2 < NT) stage_half(Wn, K, HTB(BUF, 1, 0), tid);                \
        asm volatile("s_waitcnt lgkmcnt(4)" ::: "memory");                     \
        MFMA_BANK(0, 4)                                                        \
        __builtin_amdgcn_s_barrier();                                          \
        /* ---- phase 3 ---- */                                                \
        if (t + 2 < NT) { asm volatile("s_waitcnt vmcnt(2)" ::: "memory"); }   \
        else            { asm volatile("s_waitcnt vmcnt(0)" ::: "memory"); }   \
        if (t + 1 < NT) { const char* AhN = HTB(BUF ^ 1, 0, wm); LOAD_A_BANK(0, AhN, 0) } \
        if (t + 2 < NT) stage_half(Wn + (size_t)128 * K, K, HTB(BUF, 1, 1), tid); \
        if (t + 1 < NT) { asm volatile("s_waitcnt lgkmcnt(4)" ::: "memory"); } \
        else            { asm volatile("s_waitcnt lgkmcnt(0)" ::: "memory"); } \
        MFMA_BANK(1, 6)                                                        \
        if (t + 1 < NT) {                                                      \
            const char* BhN = HTB(BUF ^ 1, 1, wn >> 1);                        \
            _Pragma("unroll")                                                  \
            for (int n = 0; n < 4; ++n) {                                      \
                bf[n][0] = lds_frag(BhN, br0 + n * 16 + lr, k0off);            \
                bf[n][1] = lds_frag(BhN, br0 + n * 16 + lr, 64 + k0off);       \
            }                                                                  \
        }                                                                      \
        __builtin_amdgcn_s_barrier();                                          \
    }

    int t;
    for (int u = 0; u < (NT >> 1); ++u) {
        t = 2 * u;     TILE(0)
        t = 2 * u + 1; TILE(1)
    }
#undef TILE
#undef LOAD_A_BANK
#undef MFMA_BANK
#undef HTB

    // ---- epilogue ----
    const int cb = n0 + wn * 64;
    float bv[4];
#pragma unroll
    for (int n = 0; n < 4; ++n) bv[n] = bias[cb + n * 16 + lr];

#pragma unroll
    for (int f = 0; f < 8; ++f) {
        const int mbase = m0 + wm * 128 + f * 16 + hi * 4;
#pragma unroll
        for (int n = 0; n < 4; ++n) {
            const int col = cb + n * 16 + lr;
#pragma unroll
            for (int r = 0; r < 4; ++r) {
                const int m = mbase + r;
                float v = acc[f][n][r] + bv[n];
                if constexpr (EPI == 0) {
                    ((unsigned short*)outv)[(size_t)m * N + col] = f2bf(v);
                } else if constexpr (EPI == 1) {
                    const int bb = m >> 12;
                    const int lw = m & 4095;
                    const int ll = (lw + SHIFTSZ) & 4095;
                    const size_t di = ((size_t)(bb << 12) + ll) * (size_t)N + col;
                    ((float*)outv)[di] = resid[di] + v;
                } else if constexpr (EPI == 2) {
                    const float g = 0.5f * v * (1.0f + erff(v * 0.70710678118654752f));
                    ((unsigned short*)outv)[(size_t)m * N + col] = f2bf(g);
                } else {
                    float* o = (float*)outv;
                    const size_t di = (size_t)m * N + col;
                    o[di] = o[di] + v;
                }
            }
        }
    }
}

// ---------------- windowed attention: one block per (window, head) ----------------
// K staged via global_load_lds into XOR-swizzled LDS (conflict-free b128 reads).
// V staged via coalesced uint4 global loads + swizzled LDS-transpose writes
// (2-way write conflicts = free; conflict-free b128 reads).
__device__ __forceinline__ bf16x8 vt_frag(const char* vt, int d, int kbyte)
{
    const int key = ((d >> 3) & 7) << 4;
    return *(const bf16x8*)(vt + d * 272 + (kbyte ^ key));
}

__launch_bounds__(256, 2)
__global__ void attn_kernel(const unsigned short* __restrict__ qkv, const float* __restrict__ rpb,
                            unsigned short* __restrict__ outp)
{
    __shared__ __align__(16) char          Ks[128 * 128];       // 16 KB, swizzled [128][64] bf16
    __shared__ __align__(16) unsigned short P[WINSZ][136];      // 34 KB
    __shared__ __align__(16) unsigned short VTl[64 * 136];      // 17 KB, swizzled V^T

    const int t   = threadIdx.x;
    const int l   = t & 63;
    const int w   = t >> 6;
    const int lr  = l & 15;
    const int lq  = l >> 4;
    const int lk  = lq * 8;
    const int blk = blockIdx.x;
    const int win = blk >> 4;
    const int h   = blk & 15;
    const bool masked = ((win & (NWIN - 1)) == NWIN - 1);

    const unsigned short* qb = qkv + (size_t)(win * WINSZ) * (3 * EMBED) + h * HD;
    const unsigned short* kb = qb + EMBED;
    const unsigned short* vb = qb + 2 * EMBED;

    // ---- stage K: 128 rows x 64 cols, ldk = 3072, inverse-swizzled source ----
    {
        const int c = t & 7;
#pragma unroll
        for (int p = 0; p < 4; ++p) {
            const int r  = (t >> 3) + p * 32;
            const int cg = (c ^ (r & 7)) << 3;
            GLDS16(kb + (size_t)r * (3 * EMBED) + cg, Ks + p * 4096 + t * 16);
        }
    }
    // ---- stage V^T: coalesced reads, swizzled transpose writes ----
    {
        const int c = t & 7;           // chunk: d-range c*8..c*8+7
#pragma unroll
        for (int p = 0; p < 4; ++p) {
            const int k = (t >> 3) + p * 32;
            const uint4 v = *(const uint4*)(vb + (size_t)k * (3 * EMBED) + c * 8);
            const unsigned int vals[4] = {v.x, v.y, v.z, v.w};
            char* base = (char*)VTl;
#pragma unroll
            for (int e2 = 0; e2 < 4; ++e2) {
                const int d0 = c * 8 + e2 * 2;
                const int key = c << 4;
                *(unsigned short*)(base + d0 * 272 + ((2 * k) ^ key))       = (unsigned short)(vals[e2] & 0xffff);
                *(unsigned short*)(base + (d0 + 1) * 272 + ((2 * k) ^ key)) = (unsigned short)(vals[e2] >> 16);
            }
        }
    }
    asm volatile("s_waitcnt vmcnt(0)" ::: "memory");
    __syncthreads();

    // ---- QK^T : wave w owns rows [32w, 32w+32), all 128 cols ----
    const int mrow = w * 32;
    f32x4 sacc[2][8];
#pragma unroll
    for (int a = 0; a < 2; ++a)
#pragma unroll
        for (int b = 0; b < 8; ++b)
            sacc[a][b] = (f32x4){0.f, 0.f, 0.f, 0.f};

#pragma unroll
    for (int ks = 0; ks < 2; ++ks) {
        const int kby = ks * 64 + lq * 16;
        bf16x8 aq[2], bk8[8];
#pragma unroll
        for (int mi = 0; mi < 2; ++mi)
            aq[mi] = *(const bf16x8*)(qb + (size_t)(mrow + mi * 16 + lr) * (3 * EMBED) + ks * 32 + lk);
#pragma unroll
        for (int ni = 0; ni < 8; ++ni)
            bk8[ni] = lds_frag(Ks, ni * 16 + lr, kby);
#pragma unroll
        for (int mi = 0; mi < 2; ++mi)
#pragma unroll
            for (int ni = 0; ni < 8; ++ni)
                sacc[mi][ni] = __builtin_amdgcn_mfma_f32_16x16x32_bf16(aq[mi], bk8[ni], sacc[mi][ni], 0, 0, 0);
    }

    // ---- in-register softmax per row ----
#pragma unroll
    for (int mi = 0; mi < 2; ++mi)
#pragma unroll
        for (int r = 0; r < 4; ++r) {
            const int i = mrow + mi * 16 + lq * 4 + r;
            float v[8];
            float mx = -1e30f;
#pragma unroll
            for (int ni = 0; ni < 8; ++ni) {
                const int j = ni * 16 + lr;
                float sv = sacc[mi][ni][r] * ATT_SCALE + rpb[(j - i + WINSZ - 1) * HEADS + h];
                if (masked && ((i >= SHIFTSZ) != (j >= SHIFTSZ))) sv -= 100.0f;
                v[ni] = sv;
                mx = fmaxf(mx, sv);
            }
#pragma unroll
            for (int s = 1; s < 16; s <<= 1) mx = fmaxf(mx, __shfl_xor(mx, s));
            float sm = 0.f;
#pragma unroll
            for (int ni = 0; ni < 8; ++ni) {
                const float p = __expf(v[ni] - mx);
                v[ni] = p;
                sm += p;
            }
#pragma unroll
            for (int s = 1; s < 16; s <<= 1) sm += __shfl_xor(sm, s);
            const float rs = 1.0f / sm;
#pragma unroll
            for (int ni = 0; ni < 8; ++ni)
                P[i][ni * 16 + lr] = f2bf(v[ni] * rs);
        }

    __syncthreads();

    // ---- PV : wave w rows [32w, 32w+32), cols 0..63, K = 128 ----
    f32x4 oacc[2][4];
#pragma unroll
    for (int a = 0; a < 2; ++a)
#pragma unroll
        for (int b = 0; b < 4; ++b)
            oacc[a][b] = (f32x4){0.f, 0.f, 0.f, 0.f};

#pragma unroll
    for (int ks = 0; ks < 4; ++ks) {
        const int k0 = ks * 32;
        bf16x8 ap[2], av[4];
#pragma unroll
        for (int mi = 0; mi < 2; ++mi)
            ap[mi] = *(const bf16x8*)(&P[mrow + mi * 16 + lr][k0 + lk]);
#pragma unroll
        for (int ni = 0; ni < 4; ++ni)
            av[ni] = vt_frag((const char*)VTl, ni * 16 + lr, k0 * 2 + lq * 16);
#pragma unroll
        for (int mi = 0; mi < 2; ++mi)
#pragma unroll
            for (int ni = 0; ni < 4; ++ni)
                oacc[mi][ni] = __builtin_amdgcn_mfma_f32_16x16x32_bf16(ap[mi], av[ni], oacc[mi][ni], 0, 0, 0);
    }

    unsigned short* ob = outp + (size_t)(win * WINSZ) * EMBED + h * HD;
#pragma unroll
    for (int mi = 0; mi < 2; ++mi)
#pragma unroll
        for (int ni = 0; ni < 4; ++ni)
#pragma unroll
            for (int r = 0; r < 4; ++r) {
                const int i = mrow + mi * 16 + lq * 4 + r;
                const int d = ni * 16 + lr;
                ob[(size_t)i * EMBED + d] = f2bf(oacc[mi][ni][r]);
            }
}

// ---------------- launcher ----------------
extern "C" void kernel_launch(void* const* d_in, const int* in_sizes, int n_in,
                              void* d_out, int out_size, void* d_ws, size_t ws_size,
                              hipStream_t stream)
{
    const float* x      = (const float*)d_in[0];
    const float* qkv_w  = (const float*)d_in[1];
    const float* qkv_b  = (const float*)d_in[2];
    const float* proj_w = (const float*)d_in[3];
    const float* proj_b = (const float*)d_in[4];
    const float* rpb    = (const float*)d_in[5];
    const float* n1w    = (const float*)d_in[6];
    const float* n1b    = (const float*)d_in[7];
    const float* n2w    = (const float*)d_in[8];
    const float* n2b    = (const float*)d_in[9];
    const float* w1     = (const float*)d_in[10];
    const float* b1     = (const float*)d_in[11];
    const float* w2     = (const float*)d_in[12];
    const float* b2     = (const float*)d_in[13];
    float* out = (float*)d_out;

    unsigned short* wqkv  = (unsigned short*)d_ws;                    // 3072*1024
    unsigned short* wproj = wqkv  + (size_t)3072 * 1024;              // 1024*1024
    unsigned short* wm1   = wproj + (size_t)1024 * 1024;              // 4096*1024
    unsigned short* wm2   = wm1   + (size_t)4096 * 1024;              // 4096*1024
    unsigned short* bufA  = wm2   + (size_t)4096 * 1024;              // 32768*1024
    unsigned short* bufB  = bufA  + (size_t)MTOT * EMBED;             // 32768*3072

    wconv<<<3072, 256, 0, stream>>>(qkv_w, wqkv, 3 * EMBED * EMBED);
    wconv<<<1024, 256, 0, stream>>>(proj_w, wproj, EMBED * EMBED);
    wconv<<<4096, 256, 0, stream>>>(w1, wm1, 4 * EMBED * EMBED);
    wconv<<<4096, 256, 0, stream>>>(w2, wm2, 4 * EMBED * EMBED);

    // h = LN1(x) rolled by -SHIFT
    ln_kernel<<<8192, 256, 0, stream>>>(x, n1w, n1b, bufA, SHIFTSZ);

    // qkv = h @ qkv_w^T + qkv_b   (M=32768, N=3072, K=1024)
    gemm256<0><<<dim3(1536), 512, 0, stream>>>(bufA, wqkv, qkv_b, bufB, nullptr, MTOT, 3 * EMBED, EMBED);

    // windowed attention -> bufA
    attn_kernel<<<4096, 256, 0, stream>>>(bufB, rpb, bufA);

    // x2 = x + roll(attn @ proj_w^T + proj_b, +SHIFT)
    gemm256<1><<<dim3(512), 512, 0, stream>>>(bufA, wproj, proj_b, out, x, MTOT, EMBED, EMBED);

    // h2 = LN2(x2)
    ln_kernel<<<8192, 256, 0, stream>>>(out, n2w, n2b, bufA, 0);

    // MLP chunked (2 x 16384 rows)
    for (int c = 0; c < 2; ++c) {
        const size_t r0 = (size_t)c * 16384;
        gemm256<2><<<dim3(1024), 512, 0, stream>>>(bufA + r0 * EMBED, wm1, b1, bufB, nullptr,
                                                   16384, 4 * EMBED, EMBED);
        gemm256<3><<<dim3(256), 512, 0, stream>>>(bufB, wm2, b2, out + r0 * EMBED, nullptr,
                                                  16384, EMBED, 4 * EMBED);
    }
}